// Round 10
// baseline (2806.616 us; speedup 1.0000x reference)
//
#include <hip/hip_runtime.h>

// T=256, B=128, H=2048. M = T*B = 32768.
// ws layout (bytes):
//   XP     @ 0          : 134217728   (xproj/h overlay, bf16, block-major slices)
//   WT_in  @ 134217728  : 8388608     (w_in^T bf16, [n][k])
//   WT_rec @ 142606336  : 8388608     (w_rec^T bf16, [n][k])
//   BAR    @ 152043520  : 32768       (per-wave ready flags: 4KB used)
//   Xb     @ 152076288  : 134217728   (x as bf16, ONLY if ws_size >= 286 MB)
//
// ROUND 6 CHANGES (latency-chain attack; overlay + protocol kept from R5):
//  (1) consumer register-prefetch: all 32 h-fragment loads issued into
//      uint4 ha[16]/hb[16] (static indices -> VGPRs) BEFORE the MFMA loop.
//      At 1 wave/SIMD nothing else hides L3/L2 latency; batching cuts the
//      h-load phase from ~2us to ~0.5us/step.
//  (2) per-wave rdy flags: flag[(g*64+nb)*4+wv] = t+1 published by each wave
//      after ITS OWN s_waitcnt(0) drain -- block-wide __syncthreads moved off
//      the publish critical path. Consumer wave polls its 16 producers x 4
//      waves = 64 contiguous flags (one per lane, coalesced 256B).
//      Ordering per wave: atomic h stores -> s_waitcnt(0) -> release fence
//      (compiler order) -> flag store. Same strength as the verified R5 chain.

typedef __bf16 bf16x8 __attribute__((ext_vector_type(8)));
typedef float f32x4 __attribute__((ext_vector_type(4)));

__device__ __forceinline__ unsigned short f32_to_bf16(float f) {
    unsigned int u = __builtin_bit_cast(unsigned int, f);
    u += 0x7FFFu + ((u >> 16) & 1u);   // round-to-nearest-even
    return (unsigned short)(u >> 16);
}
__device__ __forceinline__ float bf16_to_f32(unsigned short s) {
    unsigned int u = ((unsigned int)s) << 16;
    return __builtin_bit_cast(float, u);
}
__device__ __forceinline__ uint4 pack8(float4 a, float4 b) {
    uint4 r;
    r.x = (unsigned int)f32_to_bf16(a.x) | ((unsigned int)f32_to_bf16(a.y) << 16);
    r.y = (unsigned int)f32_to_bf16(a.z) | ((unsigned int)f32_to_bf16(a.w) << 16);
    r.z = (unsigned int)f32_to_bf16(b.x) | ((unsigned int)f32_to_bf16(b.y) << 16);
    r.w = (unsigned int)f32_to_bf16(b.z) | ((unsigned int)f32_to_bf16(b.w) << 16);
    return r;
}
__device__ __forceinline__ void gload_lds16(const void* g, void* l) {
    __builtin_amdgcn_global_load_lds(
        (const __attribute__((address_space(1))) void*)g,
        (__attribute__((address_space(3))) void*)l, 16, 0, 0);
}

// ---------------------------------------------------------------------------
// Kernel 1: fp32 (2048x2048, [k][n]) -> bf16 transposed ([n][k]) via LDS tile.
// ---------------------------------------------------------------------------
__global__ __launch_bounds__(256)
void cvt_transpose(const float* __restrict__ W, unsigned short* __restrict__ WT) {
    __shared__ unsigned short tile[64][68];
    const int tid = threadIdx.x;
    const int n0 = (blockIdx.x & 31) * 64;
    const int k0 = (blockIdx.x >> 5) * 64;
    const int rr = tid >> 4;
    const int cc = (tid & 15) * 4;
#pragma unroll
    for (int p = 0; p < 4; ++p) {
        const int k = rr + p * 16;
        const float4 v = *(const float4*)(W + (size_t)(k0 + k) * 2048 + n0 + cc);
        tile[cc + 0][k] = f32_to_bf16(v.x);
        tile[cc + 1][k] = f32_to_bf16(v.y);
        tile[cc + 2][k] = f32_to_bf16(v.z);
        tile[cc + 3][k] = f32_to_bf16(v.w);
    }
    __syncthreads();
#pragma unroll
    for (int p = 0; p < 4; ++p) {
        const int n = rr + p * 16;
        unsigned int lo = (unsigned int)tile[n][cc]     | ((unsigned int)tile[n][cc + 1] << 16);
        unsigned int hi = (unsigned int)tile[n][cc + 2] | ((unsigned int)tile[n][cc + 3] << 16);
        uint2 ov; ov.x = lo; ov.y = hi;
        *(uint2*)(WT + (size_t)(n0 + n) * 2048 + k0 + cc) = ov;
    }
}

// ---------------------------------------------------------------------------
// Kernel 1b: X f32 -> bf16 (same layout), grid-stride.
// ---------------------------------------------------------------------------
__global__ __launch_bounds__(256)
void cvt_x(const float* __restrict__ X, unsigned short* __restrict__ Xb) {
    const size_t stride = 2048 * 256;
    for (size_t i = (size_t)blockIdx.x * 256 + threadIdx.x; i < 8388608; i += stride) {
        const float4 a = *(const float4*)(X + i * 8);
        const float4 b = *(const float4*)(X + i * 8 + 4);
        const uint4 r = pack8(a, b);
        *(uint4*)(Xb + i * 8) = r;
    }
}

// Shared epilogue: write acc into block-major fragment-layout XP.
#define XPROJ_EPILOGUE()                                                        \
    {                                                                           \
        const int t = bid >> 4;                                                 \
        _Pragma("unroll")                                                       \
        for (int i = 0; i < 4; ++i) {                                           \
            const int brow = wm + i * 16;          /* multiple of 16 */         \
            const int g2   = brow >> 5;                                         \
            const int h2   = (brow & 31) >> 4;                                  \
            _Pragma("unroll")                                                   \
            for (int j = 0; j < 4; ++j) {                                       \
                const int col = n0 + wn + j * 16 + lcol;                        \
                const int nb2 = col >> 5;                                       \
                const int cc  = col & 31;                                       \
                const size_t base = (((size_t)t * 4 + g2) * 64 + nb2) * 1024    \
                                  + (size_t)h2 * 512                            \
                                  + (size_t)(cc >> 3) * 128 + (cc & 7);         \
                _Pragma("unroll")                                               \
                for (int r = 0; r < 4; ++r)                                     \
                    XP[base + (size_t)(quad * 4 + r) * 8] =                     \
                        f32_to_bf16(acc[i][j][r]);                              \
            }                                                                   \
        }                                                                       \
    }

// ---------------------------------------------------------------------------
// Kernel 2a: xproj GEMM, f32 A path (fallback). 128x128 tile, BK=32.
// ---------------------------------------------------------------------------
__global__ __launch_bounds__(256, 2)
void xproj_gemm_f32(const float* __restrict__ X, const unsigned short* __restrict__ WT,
                    unsigned short* __restrict__ XP) {
    __shared__ unsigned short As[128 * 32];
    __shared__ unsigned short Bs[128 * 32];
    const int tid  = threadIdx.x;
    const int bid  = blockIdx.x;
    const int m0   = (bid >> 4) * 128;
    const int n0   = (bid & 15) * 128;
    const int lane = tid & 63;
    const int wave = tid >> 6;
    const int wm   = (wave & 1) * 64;
    const int wn   = (wave >> 1) * 64;
    const int lcol = lane & 15;
    const int quad = lane >> 4;

    const int ar = tid >> 3;
    const int ac = (tid & 7) * 4;
    const int br = tid >> 1;
    const int bc = (tid & 1) * 16;

    f32x4 acc[4][4] = {};

    for (int kk = 0; kk < 2048; kk += 32) {
#pragma unroll
        for (int p = 0; p < 4; ++p) {
            const int r = ar + p * 32;
            const float4 v = *(const float4*)(X + (size_t)(m0 + r) * 2048 + kk + ac);
            unsigned int lo = (unsigned int)f32_to_bf16(v.x) | ((unsigned int)f32_to_bf16(v.y) << 16);
            unsigned int hi = (unsigned int)f32_to_bf16(v.z) | ((unsigned int)f32_to_bf16(v.w) << 16);
            uint2 w; w.x = lo; w.y = hi;
            *(uint2*)(As + r * 32 + ac) = w;
        }
        {
            const unsigned short* g = WT + (size_t)(n0 + br) * 2048 + kk + bc;
            const uint4 v0 = *(const uint4*)(g);
            const uint4 v1 = *(const uint4*)(g + 8);
            *(uint4*)(Bs + br * 32 + bc)     = v0;
            *(uint4*)(Bs + br * 32 + bc + 8) = v1;
        }
        __syncthreads();
        bf16x8 af[4], bf[4];
#pragma unroll
        for (int i = 0; i < 4; ++i)
            af[i] = __builtin_bit_cast(bf16x8, *(const uint4*)(As + (wm + i * 16 + lcol) * 32 + quad * 8));
#pragma unroll
        for (int j = 0; j < 4; ++j)
            bf[j] = __builtin_bit_cast(bf16x8, *(const uint4*)(Bs + (wn + j * 16 + lcol) * 32 + quad * 8));
#pragma unroll
        for (int i = 0; i < 4; ++i)
#pragma unroll
            for (int j = 0; j < 4; ++j)
                acc[i][j] = __builtin_amdgcn_mfma_f32_16x16x32_bf16(af[i], bf[j], acc[i][j], 0, 0, 0);
        __syncthreads();
    }
    XPROJ_EPILOGUE()
}

// ---------------------------------------------------------------------------
// Kernel 2b: xproj GEMM, bf16 A path via global_load_lds (width 16).
// Only runs if ws_size grants the Xb buffer.
// ---------------------------------------------------------------------------
__global__ __launch_bounds__(256, 2)
void xproj_gemm_bf16(const unsigned short* __restrict__ Xb,
                     const unsigned short* __restrict__ WT,
                     unsigned short* __restrict__ XP) {
    __shared__ unsigned short As[128 * 32];
    __shared__ unsigned short Bs[128 * 32];
    const int tid  = threadIdx.x;
    const int bid  = blockIdx.x;
    const int m0   = (bid >> 4) * 128;
    const int n0   = (bid & 15) * 128;
    const int lane = tid & 63;
    const int wave = tid >> 6;
    const int wm   = (wave & 1) * 64;
    const int wn   = (wave >> 1) * 64;
    const int lcol = lane & 15;
    const int quad = lane >> 4;

    const int srow = lane >> 2;        // 0..15
    const int scol = (lane & 3) * 8;   // shorts

    f32x4 acc[4][4] = {};

    for (int kk = 0; kk < 2048; kk += 32) {
#pragma unroll
        for (int q = 0; q < 2; ++q) {
            const int r = wave * 32 + q * 16 + srow;
            gload_lds16(Xb + (size_t)(m0 + r) * 2048 + kk + scol,
                        As + wave * 1024 + q * 512);
            gload_lds16(WT + (size_t)(n0 + r) * 2048 + kk + scol,
                        Bs + wave * 1024 + q * 512);
        }
        __syncthreads();
        bf16x8 af[4], bf[4];
#pragma unroll
        for (int i = 0; i < 4; ++i)
            af[i] = __builtin_bit_cast(bf16x8, *(const uint4*)(As + (wm + i * 16 + lcol) * 32 + quad * 8));
#pragma unroll
        for (int j = 0; j < 4; ++j)
            bf[j] = __builtin_bit_cast(bf16x8, *(const uint4*)(Bs + (wn + j * 16 + lcol) * 32 + quad * 8));
#pragma unroll
        for (int i = 0; i < 4; ++i)
#pragma unroll
            for (int j = 0; j < 4; ++j)
                acc[i][j] = __builtin_amdgcn_mfma_f32_16x16x32_bf16(af[i], bf[j], acc[i][j], 0, 0, 0);
        __syncthreads();
    }
    XPROJ_EPILOGUE()
}

// ---------------------------------------------------------------------------
// Kernel 3: persistent recurrence, h-in-XP overlay + per-wave flags +
// register-prefetched h loads.
// 256 blocks x 256 threads. g = (bid&7)>>1 (XCD-affine), nb = col block 0..63.
// Wave w consumes kb in [16w,16w+16). flag[(g*64+nb)*4+wv] = t+1 <=> wave wv
// of block (g,nb) has h@t drained to L3.
// ---------------------------------------------------------------------------
__global__ __launch_bounds__(256, 1)
void rnn_scan(unsigned short* __restrict__ XP,
              const unsigned short* __restrict__ WT,
              const float* __restrict__ bias,
              float* __restrict__ out,
              unsigned int* __restrict__ bar) {
    __shared__ unsigned short Ws[64 * 2 * 512];   // fragment-major, 128 KB
    __shared__ float red[4 * 1024];               // 4 wave-partials of 32x32
    const int tid  = threadIdx.x;
    const int bid  = blockIdx.x;
    const int g    = (bid & 7) >> 1;               // batch group (XCD-affine)
    const int nb   = ((bid >> 3) << 1) | (bid & 1);// column block 0..63
    const int n0   = nb * 32;
    const int m0   = g * 32;
    const int lane = tid & 63;
    const int wave = tid >> 6;
    const int lcol = lane & 15;
    const int quad = lane >> 4;

    // per-wave flags: own flag + the 64 flags of my chunk's producers
    unsigned int* rdy_own = bar + (g * 64 + nb) * 4 + wave;
    const unsigned int* rdy_poll = bar + g * 256 + wave * 64 + lane;  // coalesced

    // stage w_rec^T slice into LDS in B-fragment-major layout:
    // frag (kb, half): lane L holds B[n = 16*half + (L&15)][k = 32*kb + 8*(L>>4) + j]
    {
        const int r    = tid >> 3;          // local col n 0..31
        const int half = r >> 4;
        const int lc   = r & 15;
        const int ch   = (tid & 7) * 256;   // k start
        const unsigned short* src = WT + (size_t)(n0 + r) * 2048 + ch;
#pragma unroll
        for (int c = 0; c < 32; ++c) {
            const int k    = ch + c * 8;
            const int kb   = k >> 5;
            const int qd   = (k & 31) >> 3;
            unsigned short* dst = Ws + (kb * 2 + half) * 512 + (qd * 16 + lc) * 8;
            *(uint4*)dst = *(const uint4*)(src + c * 8);
        }
    }
    const int erow = tid >> 3;          // epilogue: 4 elems per thread
    const int ecol = (tid & 7) * 4;
    const float4 b4 = *(const float4*)(bias + n0 + ecol);
    // in-slice offset (shorts) of this thread's 4 elems (8 B aligned)
    const size_t eoff = (size_t)(erow >> 4) * 512
                      + (size_t)((ecol >> 3) * 16 + (erow & 15)) * 8 + (ecol & 7);
    __syncthreads();

    for (int t = 0; t < 256; ++t) {
        unsigned short* slice_own = XP + (((size_t)t * 4 + g) * 64 + nb) * 1024;
        // xproj read: bypass load keeps own-slice lines out of caches so the
        // later h@t write leaves no stale copy anywhere.
        const unsigned long long xp8 = __hip_atomic_load(
            (const unsigned long long*)(slice_own + eoff),
            __ATOMIC_RELAXED, __HIP_MEMORY_SCOPE_AGENT);
        const uint2 xpu = __builtin_bit_cast(uint2, xp8);
        float4 sum = {0.f, 0.f, 0.f, 0.f};
        if (t > 0) {
            // wait for all 4 waves of my chunk's 16 producers (64 flags, 1/lane)
            while (__hip_atomic_load(rdy_poll, __ATOMIC_RELAXED, __HIP_MEMORY_SCOPE_AGENT) < (unsigned)t)
                __builtin_amdgcn_s_sleep(1);
            __builtin_amdgcn_fence(__ATOMIC_ACQUIRE, "workgroup");

            // h@{t-1} fragments: PLAIN cached loads, ALL issued before use
            // (uint4 ha[16]/hb[16], static indices -> stays in VGPRs).
            const unsigned short* hbase =
                XP + (((size_t)(t - 1) * 4 + g) * 64 + wave * 16) * 1024 + lane * 8;
            uint4 ha[16], hb[16];
#pragma unroll
            for (int it = 0; it < 16; ++it) {
                ha[it] = *(const uint4*)(hbase + it * 1024);
                hb[it] = *(const uint4*)(hbase + it * 1024 + 512);
            }
            const unsigned short* b0p = Ws + (wave * 16 * 2) * 512 + lane * 8;  // half 0
            const unsigned short* b1p = b0p + 512;                              // half 1
            f32x4 a00 = {}, a01 = {}, a10 = {}, a11 = {};
#pragma unroll
            for (int it = 0; it < 16; ++it) {
                bf16x8 a0 = __builtin_bit_cast(bf16x8, ha[it]);
                bf16x8 a1 = __builtin_bit_cast(bf16x8, hb[it]);
                bf16x8 b0 = __builtin_bit_cast(bf16x8, *(const uint4*)(b0p + it * 1024));
                bf16x8 b1 = __builtin_bit_cast(bf16x8, *(const uint4*)(b1p + it * 1024));
                a00 = __builtin_amdgcn_mfma_f32_16x16x32_bf16(a0, b0, a00, 0, 0, 0);
                a01 = __builtin_amdgcn_mfma_f32_16x16x32_bf16(a0, b1, a01, 0, 0, 0);
                a10 = __builtin_amdgcn_mfma_f32_16x16x32_bf16(a1, b0, a10, 0, 0, 0);
                a11 = __builtin_amdgcn_mfma_f32_16x16x32_bf16(a1, b1, a11, 0, 0, 0);
            }
            float* rw = red + wave * 1024;
#pragma unroll
            for (int r = 0; r < 4; ++r) {
                rw[(quad * 4 + r) * 32 + lcol]           = a00[r];
                rw[(quad * 4 + r) * 32 + 16 + lcol]      = a01[r];
                rw[(16 + quad * 4 + r) * 32 + lcol]      = a10[r];
                rw[(16 + quad * 4 + r) * 32 + 16 + lcol] = a11[r];
            }
            __syncthreads();   // (A) red ready
            const float4 s0v = *(const float4*)(red + 0 * 1024 + tid * 4);
            const float4 s1v = *(const float4*)(red + 1 * 1024 + tid * 4);
            const float4 s2v = *(const float4*)(red + 2 * 1024 + tid * 4);
            const float4 s3v = *(const float4*)(red + 3 * 1024 + tid * 4);
            sum.x = (s0v.x + s1v.x) + (s2v.x + s3v.x);
            sum.y = (s0v.y + s1v.y) + (s2v.y + s3v.y);
            sum.z = (s0v.z + s1v.z) + (s2v.z + s3v.z);
            sum.w = (s0v.w + s1v.w) + (s2v.w + s3v.w);
        }
        float4 v;
        v.x = tanhf(bf16_to_f32((unsigned short)(xpu.x & 0xFFFFu)) + sum.x + b4.x);
        v.y = tanhf(bf16_to_f32((unsigned short)(xpu.x >> 16))     + sum.y + b4.y);
        v.z = tanhf(bf16_to_f32((unsigned short)(xpu.y & 0xFFFFu)) + sum.z + b4.z);
        v.w = tanhf(bf16_to_f32((unsigned short)(xpu.y >> 16))     + sum.w + b4.w);
        if (t < 255) {
            unsigned long long pv =
                  (unsigned long long)((unsigned int)f32_to_bf16(v.x) | ((unsigned int)f32_to_bf16(v.y) << 16))
                | ((unsigned long long)((unsigned int)f32_to_bf16(v.z) | ((unsigned int)f32_to_bf16(v.w) << 16)) << 32);
            __hip_atomic_store((unsigned long long*)(slice_own + eoff), pv,
                               __ATOMIC_RELAXED, __HIP_MEMORY_SCOPE_AGENT);
            __builtin_amdgcn_s_waitcnt(0);   // drain THIS wave's h stores to L3
            __builtin_amdgcn_fence(__ATOMIC_RELEASE, "workgroup");  // compiler order
            if (lane == 0)                   // per-wave publish (no block sync)
                __hip_atomic_store(rdy_own, (unsigned)(t + 1),
                                   __ATOMIC_RELAXED, __HIP_MEMORY_SCOPE_AGENT);
            __syncthreads();                 // (B) guards red reuse (off pub path)
        } else {
            *(float4*)(out + (size_t)(m0 + erow) * 2048 + n0 + ecol) = v;
        }
    }
}

// ---------------------------------------------------------------------------
extern "C" void kernel_launch(void* const* d_in, const int* in_sizes, int n_in,
                              void* d_out, int out_size, void* d_ws, size_t ws_size,
                              hipStream_t stream) {
    const float* x     = (const float*)d_in[0];
    const float* w_in  = (const float*)d_in[1];
    const float* w_rec = (const float*)d_in[2];
    const float* bias  = (const float*)d_in[3];
    float* out = (float*)d_out;

    char* ws = (char*)d_ws;
    unsigned short* XP     = (unsigned short*)(ws);
    unsigned short* WT_in  = (unsigned short*)(ws + 134217728);
    unsigned short* WT_rec = (unsigned short*)(ws + 134217728 + 8388608);
    unsigned int*   BAR    = (unsigned int*)(ws + 152043520);
    unsigned short* Xb     = (unsigned short*)(ws + 152076288);

    hipMemsetAsync(BAR, 0, 32768, stream);
    cvt_transpose<<<dim3(1024), dim3(256), 0, stream>>>(w_in,  WT_in);
    cvt_transpose<<<dim3(1024), dim3(256), 0, stream>>>(w_rec, WT_rec);

    if (ws_size >= 286294016ull) {
        cvt_x<<<dim3(2048), dim3(256), 0, stream>>>(x, Xb);
        xproj_gemm_bf16<<<dim3(4096), dim3(256), 0, stream>>>(Xb, WT_in, XP);
    } else {
        xproj_gemm_f32<<<dim3(4096), dim3(256), 0, stream>>>(x, WT_in, XP);
    }

    void* args[] = {(void*)&XP, (void*)&WT_rec, (void*)&bias,
                    (void*)&out, (void*)&BAR};
    hipLaunchCooperativeKernel(reinterpret_cast<void*>(rnn_scan),
                               dim3(256), dim3(256), args, 0, stream);
}

// Round 13
// 2298.362 us; speedup vs baseline: 1.2211x; 1.2211x over previous
//
#include <hip/hip_runtime.h>

// T=256, B=128, H=2048. M = T*B = 32768.
// ws layout (bytes):
//   XP     @ 0          : 134217728   (xproj/h overlay, bf16, block-major slices)
//   WT_in  @ 134217728  : 8388608     (w_in^T bf16, [n][k])
//   WT_rec @ 142606336  : 8388608     (w_rec^T bf16, [n][k])
//   BAR    @ 152043520  : 32768       (block-level ready flags, 64B stride)
//   Xb     @ 152076288  : 134217728   (x as bf16, ONLY if ws_size >= 286 MB)
//
// ROUND 10: revert R6 (per-wave flags regressed 1545->2065; VGPR=132 proved
// the prefetch batch was a codegen no-op). Scan = verified R5 overlay scan
// with ONE change: epilogue thread->element mapping is now FRAGMENT-LINEAR
// (eoff = tid*4 shorts -> wave stores/loads 512B contiguous on the h path),
// and red holds wave-partials in fragment layout so the epilogue read
// (red + w*1024 + tid*4) is unchanged and conflict-free. Numerics identical.

typedef __bf16 bf16x8 __attribute__((ext_vector_type(8)));
typedef float f32x4 __attribute__((ext_vector_type(4)));

__device__ __forceinline__ unsigned short f32_to_bf16(float f) {
    unsigned int u = __builtin_bit_cast(unsigned int, f);
    u += 0x7FFFu + ((u >> 16) & 1u);   // round-to-nearest-even
    return (unsigned short)(u >> 16);
}
__device__ __forceinline__ float bf16_to_f32(unsigned short s) {
    unsigned int u = ((unsigned int)s) << 16;
    return __builtin_bit_cast(float, u);
}
__device__ __forceinline__ uint4 pack8(float4 a, float4 b) {
    uint4 r;
    r.x = (unsigned int)f32_to_bf16(a.x) | ((unsigned int)f32_to_bf16(a.y) << 16);
    r.y = (unsigned int)f32_to_bf16(a.z) | ((unsigned int)f32_to_bf16(a.w) << 16);
    r.z = (unsigned int)f32_to_bf16(b.x) | ((unsigned int)f32_to_bf16(b.y) << 16);
    r.w = (unsigned int)f32_to_bf16(b.z) | ((unsigned int)f32_to_bf16(b.w) << 16);
    return r;
}
__device__ __forceinline__ void gload_lds16(const void* g, void* l) {
    __builtin_amdgcn_global_load_lds(
        (const __attribute__((address_space(1))) void*)g,
        (__attribute__((address_space(3))) void*)l, 16, 0, 0);
}

// ---------------------------------------------------------------------------
// Kernel 1: fp32 (2048x2048, [k][n]) -> bf16 transposed ([n][k]) via LDS tile.
// ---------------------------------------------------------------------------
__global__ __launch_bounds__(256)
void cvt_transpose(const float* __restrict__ W, unsigned short* __restrict__ WT) {
    __shared__ unsigned short tile[64][68];
    const int tid = threadIdx.x;
    const int n0 = (blockIdx.x & 31) * 64;
    const int k0 = (blockIdx.x >> 5) * 64;
    const int rr = tid >> 4;
    const int cc = (tid & 15) * 4;
#pragma unroll
    for (int p = 0; p < 4; ++p) {
        const int k = rr + p * 16;
        const float4 v = *(const float4*)(W + (size_t)(k0 + k) * 2048 + n0 + cc);
        tile[cc + 0][k] = f32_to_bf16(v.x);
        tile[cc + 1][k] = f32_to_bf16(v.y);
        tile[cc + 2][k] = f32_to_bf16(v.z);
        tile[cc + 3][k] = f32_to_bf16(v.w);
    }
    __syncthreads();
#pragma unroll
    for (int p = 0; p < 4; ++p) {
        const int n = rr + p * 16;
        unsigned int lo = (unsigned int)tile[n][cc]     | ((unsigned int)tile[n][cc + 1] << 16);
        unsigned int hi = (unsigned int)tile[n][cc + 2] | ((unsigned int)tile[n][cc + 3] << 16);
        uint2 ov; ov.x = lo; ov.y = hi;
        *(uint2*)(WT + (size_t)(n0 + n) * 2048 + k0 + cc) = ov;
    }
}

// ---------------------------------------------------------------------------
// Kernel 1b: X f32 -> bf16 (same layout), grid-stride.
// ---------------------------------------------------------------------------
__global__ __launch_bounds__(256)
void cvt_x(const float* __restrict__ X, unsigned short* __restrict__ Xb) {
    const size_t stride = 2048 * 256;
    for (size_t i = (size_t)blockIdx.x * 256 + threadIdx.x; i < 8388608; i += stride) {
        const float4 a = *(const float4*)(X + i * 8);
        const float4 b = *(const float4*)(X + i * 8 + 4);
        const uint4 r = pack8(a, b);
        *(uint4*)(Xb + i * 8) = r;
    }
}

// Shared epilogue: write acc into block-major fragment-layout XP.
#define XPROJ_EPILOGUE()                                                        \
    {                                                                           \
        const int t = bid >> 4;                                                 \
        _Pragma("unroll")                                                       \
        for (int i = 0; i < 4; ++i) {                                           \
            const int brow = wm + i * 16;          /* multiple of 16 */         \
            const int g2   = brow >> 5;                                         \
            const int h2   = (brow & 31) >> 4;                                  \
            _Pragma("unroll")                                                   \
            for (int j = 0; j < 4; ++j) {                                       \
                const int col = n0 + wn + j * 16 + lcol;                        \
                const int nb2 = col >> 5;                                       \
                const int cc  = col & 31;                                       \
                const size_t base = (((size_t)t * 4 + g2) * 64 + nb2) * 1024    \
                                  + (size_t)h2 * 512                            \
                                  + (size_t)(cc >> 3) * 128 + (cc & 7);         \
                _Pragma("unroll")                                               \
                for (int r = 0; r < 4; ++r)                                     \
                    XP[base + (size_t)(quad * 4 + r) * 8] =                     \
                        f32_to_bf16(acc[i][j][r]);                              \
            }                                                                   \
        }                                                                       \
    }

// ---------------------------------------------------------------------------
// Kernel 2a: xproj GEMM, f32 A path (fallback). 128x128 tile, BK=32.
// ---------------------------------------------------------------------------
__global__ __launch_bounds__(256, 2)
void xproj_gemm_f32(const float* __restrict__ X, const unsigned short* __restrict__ WT,
                    unsigned short* __restrict__ XP) {
    __shared__ unsigned short As[128 * 32];
    __shared__ unsigned short Bs[128 * 32];
    const int tid  = threadIdx.x;
    const int bid  = blockIdx.x;
    const int m0   = (bid >> 4) * 128;
    const int n0   = (bid & 15) * 128;
    const int lane = tid & 63;
    const int wave = tid >> 6;
    const int wm   = (wave & 1) * 64;
    const int wn   = (wave >> 1) * 64;
    const int lcol = lane & 15;
    const int quad = lane >> 4;

    const int ar = tid >> 3;
    const int ac = (tid & 7) * 4;
    const int br = tid >> 1;
    const int bc = (tid & 1) * 16;

    f32x4 acc[4][4] = {};

    for (int kk = 0; kk < 2048; kk += 32) {
#pragma unroll
        for (int p = 0; p < 4; ++p) {
            const int r = ar + p * 32;
            const float4 v = *(const float4*)(X + (size_t)(m0 + r) * 2048 + kk + ac);
            unsigned int lo = (unsigned int)f32_to_bf16(v.x) | ((unsigned int)f32_to_bf16(v.y) << 16);
            unsigned int hi = (unsigned int)f32_to_bf16(v.z) | ((unsigned int)f32_to_bf16(v.w) << 16);
            uint2 w; w.x = lo; w.y = hi;
            *(uint2*)(As + r * 32 + ac) = w;
        }
        {
            const unsigned short* g = WT + (size_t)(n0 + br) * 2048 + kk + bc;
            const uint4 v0 = *(const uint4*)(g);
            const uint4 v1 = *(const uint4*)(g + 8);
            *(uint4*)(Bs + br * 32 + bc)     = v0;
            *(uint4*)(Bs + br * 32 + bc + 8) = v1;
        }
        __syncthreads();
        bf16x8 af[4], bf[4];
#pragma unroll
        for (int i = 0; i < 4; ++i)
            af[i] = __builtin_bit_cast(bf16x8, *(const uint4*)(As + (wm + i * 16 + lcol) * 32 + quad * 8));
#pragma unroll
        for (int j = 0; j < 4; ++j)
            bf[j] = __builtin_bit_cast(bf16x8, *(const uint4*)(Bs + (wn + j * 16 + lcol) * 32 + quad * 8));
#pragma unroll
        for (int i = 0; i < 4; ++i)
#pragma unroll
            for (int j = 0; j < 4; ++j)
                acc[i][j] = __builtin_amdgcn_mfma_f32_16x16x32_bf16(af[i], bf[j], acc[i][j], 0, 0, 0);
        __syncthreads();
    }
    XPROJ_EPILOGUE()
}

// ---------------------------------------------------------------------------
// Kernel 2b: xproj GEMM, bf16 A path via global_load_lds (width 16).
// Only runs if ws_size grants the Xb buffer.
// ---------------------------------------------------------------------------
__global__ __launch_bounds__(256, 2)
void xproj_gemm_bf16(const unsigned short* __restrict__ Xb,
                     const unsigned short* __restrict__ WT,
                     unsigned short* __restrict__ XP) {
    __shared__ unsigned short As[128 * 32];
    __shared__ unsigned short Bs[128 * 32];
    const int tid  = threadIdx.x;
    const int bid  = blockIdx.x;
    const int m0   = (bid >> 4) * 128;
    const int n0   = (bid & 15) * 128;
    const int lane = tid & 63;
    const int wave = tid >> 6;
    const int wm   = (wave & 1) * 64;
    const int wn   = (wave >> 1) * 64;
    const int lcol = lane & 15;
    const int quad = lane >> 4;

    const int srow = lane >> 2;        // 0..15
    const int scol = (lane & 3) * 8;   // shorts

    f32x4 acc[4][4] = {};

    for (int kk = 0; kk < 2048; kk += 32) {
#pragma unroll
        for (int q = 0; q < 2; ++q) {
            const int r = wave * 32 + q * 16 + srow;
            gload_lds16(Xb + (size_t)(m0 + r) * 2048 + kk + scol,
                        As + wave * 1024 + q * 512);
            gload_lds16(WT + (size_t)(n0 + r) * 2048 + kk + scol,
                        Bs + wave * 1024 + q * 512);
        }
        __syncthreads();
        bf16x8 af[4], bf[4];
#pragma unroll
        for (int i = 0; i < 4; ++i)
            af[i] = __builtin_bit_cast(bf16x8, *(const uint4*)(As + (wm + i * 16 + lcol) * 32 + quad * 8));
#pragma unroll
        for (int j = 0; j < 4; ++j)
            bf[j] = __builtin_bit_cast(bf16x8, *(const uint4*)(Bs + (wn + j * 16 + lcol) * 32 + quad * 8));
#pragma unroll
        for (int i = 0; i < 4; ++i)
#pragma unroll
            for (int j = 0; j < 4; ++j)
                acc[i][j] = __builtin_amdgcn_mfma_f32_16x16x32_bf16(af[i], bf[j], acc[i][j], 0, 0, 0);
        __syncthreads();
    }
    XPROJ_EPILOGUE()
}

// ---------------------------------------------------------------------------
// Kernel 3: persistent recurrence, h-in-XP overlay (R5 protocol) with
// fragment-linear epilogue mapping (coalesced h store/load).
// 256 blocks x 256 threads. g = (bid&7)>>1 (XCD-affine), nb = col block 0..63.
// Wave w consumes kb in [16w,16w+16). rdy[g][nb]=t+1 <=> h@t at L3.
// Thread tid owns slice shorts [4*tid, 4*tid+4):
//   row = 16*(tid>>7) + ((tid>>1)&15), col = ((tid>>5)&3)*8 + (tid&1)*4.
// red holds wave-partials in the SAME fragment layout -> epilogue reads
// red + w*1024 + tid*4 (conflict-free, unchanged code).
// ---------------------------------------------------------------------------
__global__ __launch_bounds__(256, 1)
void rnn_scan(unsigned short* __restrict__ XP,
              const unsigned short* __restrict__ WT,
              const float* __restrict__ bias,
              float* __restrict__ out,
              unsigned int* __restrict__ bar) {
    __shared__ unsigned short Ws[64 * 2 * 512];   // fragment-major, 128 KB
    __shared__ float red[4 * 1024];               // 4 wave-partials, frag layout
    const int tid  = threadIdx.x;
    const int bid  = blockIdx.x;
    const int g    = (bid & 7) >> 1;               // batch group (XCD-affine)
    const int nb   = ((bid >> 3) << 1) | (bid & 1);// column block 0..63
    const int n0   = nb * 32;
    const int m0   = g * 32;
    const int lane = tid & 63;
    const int wave = tid >> 6;
    const int lcol = lane & 15;
    const int quad = lane >> 4;

    unsigned int* rdy_own = bar + (g * 64 + nb) * 16;
    const unsigned int* rdy_poll = bar + (g * 64 + wave * 16 + lcol) * 16;  // my chunk's producers

    // stage w_rec^T slice into LDS in B-fragment-major layout:
    // frag (kb, half): lane L holds B[n = 16*half + (L&15)][k = 32*kb + 8*(L>>4) + j]
    {
        const int r    = tid >> 3;          // local col n 0..31
        const int half = r >> 4;
        const int lc   = r & 15;
        const int ch   = (tid & 7) * 256;   // k start
        const unsigned short* src = WT + (size_t)(n0 + r) * 2048 + ch;
#pragma unroll
        for (int c = 0; c < 32; ++c) {
            const int k    = ch + c * 8;
            const int kb   = k >> 5;
            const int qd   = (k & 31) >> 3;
            unsigned short* dst = Ws + (kb * 2 + half) * 512 + (qd * 16 + lc) * 8;
            *(uint4*)dst = *(const uint4*)(src + c * 8);
        }
    }
    // fragment-linear epilogue mapping: thread owns shorts [4*tid, 4*tid+4)
    const int prow = 16 * (tid >> 7) + ((tid >> 1) & 15);
    const int pcol = ((tid >> 5) & 3) * 8 + (tid & 1) * 4;
    const float4 b4 = *(const float4*)(bias + n0 + pcol);
    const size_t eoff = (size_t)tid * 4;   // shorts; 8B-aligned, wave-contiguous
    __syncthreads();

    for (int t = 0; t < 256; ++t) {
        unsigned short* slice_own = XP + (((size_t)t * 4 + g) * 64 + nb) * 1024;
        // xproj read: bypass load keeps own-slice lines out of caches so the
        // later h@t write leaves no stale copy anywhere. Wave reads 512B linear.
        const unsigned long long xp8 = __hip_atomic_load(
            (const unsigned long long*)(slice_own + eoff),
            __ATOMIC_RELAXED, __HIP_MEMORY_SCOPE_AGENT);
        const uint2 xpu = __builtin_bit_cast(uint2, xp8);
        float4 sum = {0.f, 0.f, 0.f, 0.f};
        if (t > 0) {
            // wait for MY chunk's 16 producers to have h@{t-1} at L3
            while (__hip_atomic_load(rdy_poll, __ATOMIC_RELAXED, __HIP_MEMORY_SCOPE_AGENT) < (unsigned)t)
                __builtin_amdgcn_s_sleep(1);
            __builtin_amdgcn_fence(__ATOMIC_ACQUIRE, "workgroup");

            // h@{t-1} fragments: PLAIN cached loads (unique addresses per t,
            // L2-shared across co-XCD consumers)
            const unsigned short* hbase =
                XP + (((size_t)(t - 1) * 4 + g) * 64 + wave * 16) * 1024 + lane * 8;
            const unsigned short* b0p = Ws + (wave * 16 * 2) * 512 + lane * 8;  // half 0
            const unsigned short* b1p = b0p + 512;                              // half 1
            f32x4 a00 = {}, a01 = {}, a10 = {}, a11 = {};
#pragma unroll
            for (int it = 0; it < 16; ++it) {
                bf16x8 a0 = __builtin_bit_cast(bf16x8, *(const uint4*)(hbase + it * 1024));
                bf16x8 a1 = __builtin_bit_cast(bf16x8, *(const uint4*)(hbase + it * 1024 + 512));
                bf16x8 b0 = __builtin_bit_cast(bf16x8, *(const uint4*)(b0p + it * 1024));
                bf16x8 b1 = __builtin_bit_cast(bf16x8, *(const uint4*)(b1p + it * 1024));
                a00 = __builtin_amdgcn_mfma_f32_16x16x32_bf16(a0, b0, a00, 0, 0, 0);
                a01 = __builtin_amdgcn_mfma_f32_16x16x32_bf16(a0, b1, a01, 0, 0, 0);
                a10 = __builtin_amdgcn_mfma_f32_16x16x32_bf16(a1, b0, a10, 0, 0, 0);
                a11 = __builtin_amdgcn_mfma_f32_16x16x32_bf16(a1, b1, a11, 0, 0, 0);
            }
            // wave-partial store in FRAGMENT layout:
            // off(row,col) = (row>>4)*512 + ((col>>3)*16 + (row&15))*8 + (col&7)
            float* rw = red + wave * 1024;
            const int r0 = quad * 4;
#pragma unroll
            for (int r = 0; r < 4; ++r) {
                const int row = r0 + r;
                const int c1  = 16 + lcol;
                const int o00 = ((lcol >> 3) * 16 + row) * 8 + (lcol & 7);
                const int o01 = ((c1 >> 3) * 16 + row) * 8 + (c1 & 7);
                rw[o00]       = a00[r];
                rw[o01]       = a01[r];
                rw[512 + o00] = a10[r];
                rw[512 + o01] = a11[r];
            }
            __syncthreads();   // (A) red ready
            const float4 s0v = *(const float4*)(red + 0 * 1024 + tid * 4);
            const float4 s1v = *(const float4*)(red + 1 * 1024 + tid * 4);
            const float4 s2v = *(const float4*)(red + 2 * 1024 + tid * 4);
            const float4 s3v = *(const float4*)(red + 3 * 1024 + tid * 4);
            sum.x = (s0v.x + s1v.x) + (s2v.x + s3v.x);
            sum.y = (s0v.y + s1v.y) + (s2v.y + s3v.y);
            sum.z = (s0v.z + s1v.z) + (s2v.z + s3v.z);
            sum.w = (s0v.w + s1v.w) + (s2v.w + s3v.w);
        }
        float4 v;
        v.x = tanhf(bf16_to_f32((unsigned short)(xpu.x & 0xFFFFu)) + sum.x + b4.x);
        v.y = tanhf(bf16_to_f32((unsigned short)(xpu.x >> 16))     + sum.y + b4.y);
        v.z = tanhf(bf16_to_f32((unsigned short)(xpu.y & 0xFFFFu)) + sum.z + b4.z);
        v.w = tanhf(bf16_to_f32((unsigned short)(xpu.y >> 16))     + sum.w + b4.w);
        if (t < 255) {
            unsigned long long pv =
                  (unsigned long long)((unsigned int)f32_to_bf16(v.x) | ((unsigned int)f32_to_bf16(v.y) << 16))
                | ((unsigned long long)((unsigned int)f32_to_bf16(v.z) | ((unsigned int)f32_to_bf16(v.w) << 16)) << 32);
            __hip_atomic_store((unsigned long long*)(slice_own + eoff), pv,
                               __ATOMIC_RELAXED, __HIP_MEMORY_SCOPE_AGENT);
            __builtin_amdgcn_s_waitcnt(0);   // drain: h@t at coherence point
            __syncthreads();                 // (B) whole block drained (guards red reuse)
            if (tid == 0)                    // publish h@t
                __hip_atomic_store(rdy_own, (unsigned)(t + 1), __ATOMIC_RELAXED, __HIP_MEMORY_SCOPE_AGENT);
        } else {
            *(float4*)(out + (size_t)(m0 + prow) * 2048 + n0 + pcol) = v;
        }
    }
}

// ---------------------------------------------------------------------------
extern "C" void kernel_launch(void* const* d_in, const int* in_sizes, int n_in,
                              void* d_out, int out_size, void* d_ws, size_t ws_size,
                              hipStream_t stream) {
    const float* x     = (const float*)d_in[0];
    const float* w_in  = (const float*)d_in[1];
    const float* w_rec = (const float*)d_in[2];
    const float* bias  = (const float*)d_in[3];
    float* out = (float*)d_out;

    char* ws = (char*)d_ws;
    unsigned short* XP     = (unsigned short*)(ws);
    unsigned short* WT_in  = (unsigned short*)(ws + 134217728);
    unsigned short* WT_rec = (unsigned short*)(ws + 134217728 + 8388608);
    unsigned int*   BAR    = (unsigned int*)(ws + 152043520);
    unsigned short* Xb     = (unsigned short*)(ws + 152076288);

    hipMemsetAsync(BAR, 0, 32768, stream);
    cvt_transpose<<<dim3(1024), dim3(256), 0, stream>>>(w_in,  WT_in);
    cvt_transpose<<<dim3(1024), dim3(256), 0, stream>>>(w_rec, WT_rec);

    if (ws_size >= 286294016ull) {
        cvt_x<<<dim3(2048), dim3(256), 0, stream>>>(x, Xb);
        xproj_gemm_bf16<<<dim3(4096), dim3(256), 0, stream>>>(Xb, WT_in, XP);
    } else {
        xproj_gemm_f32<<<dim3(4096), dim3(256), 0, stream>>>(x, WT_in, XP);
    }

    void* args[] = {(void*)&XP, (void*)&WT_rec, (void*)&bias,
                    (void*)&out, (void*)&BAR};
    hipLaunchCooperativeKernel(reinterpret_cast<void*>(rnn_scan),
                               dim3(256), dim3(256), args, 0, stream);
}